// Round 1
// baseline (69.587 us; speedup 1.0000x reference)
//
#include <hip/hip_runtime.h>
#include <math.h>

#define D 1024

// Pre-kernel: cos(theta), sin(theta), exp(log_scale) tables into workspace.
__global__ void rsa_make_tables(const float* __restrict__ log_scale,
                                const float* __restrict__ theta,
                                float* __restrict__ tabc,
                                float* __restrict__ tabs,
                                float* __restrict__ tabsc) {
    int i = blockIdx.x * blockDim.x + threadIdx.x;
    if (i < D) {
        float t = theta[i];
        tabc[i]  = cosf(t);
        tabs[i]  = sinf(t);
        tabsc[i] = expf(log_scale[i]);
    }
}

// One wave (64 lanes) per row of length D=1024; lane owns 16 contiguous elems.
// Sequential carry recurrence parallelized as an exact affine-map scan.
__global__ __launch_bounds__(256) void rsa_rot_kernel(
    const float* __restrict__ x,
    const float* __restrict__ tabc,
    const float* __restrict__ tabs,
    const float* __restrict__ tabsc,
    float* __restrict__ out,
    int nrows)
{
    const int lane = threadIdx.x & 63;
    const int wave = threadIdx.x >> 6;
    const int row  = blockIdx.x * 4 + wave;
    if (row >= nrows) return;

    const size_t rbase = (size_t)row * D + (size_t)lane * 16;
    const int    tbase = lane * 16;

    float xv[16], cv[16], sv[16], scv[16];
    #pragma unroll
    for (int j = 0; j < 4; ++j) {
        float4 v = *reinterpret_cast<const float4*>(x + rbase + j * 4);
        xv[j*4+0] = v.x; xv[j*4+1] = v.y; xv[j*4+2] = v.z; xv[j*4+3] = v.w;
        float4 c = *reinterpret_cast<const float4*>(tabc + tbase + j * 4);
        cv[j*4+0] = c.x; cv[j*4+1] = c.y; cv[j*4+2] = c.z; cv[j*4+3] = c.w;
        float4 s = *reinterpret_cast<const float4*>(tabs + tbase + j * 4);
        sv[j*4+0] = s.x; sv[j*4+1] = s.y; sv[j*4+2] = s.z; sv[j*4+3] = s.w;
        float4 sc = *reinterpret_cast<const float4*>(tabsc + tbase + j * 4);
        scv[j*4+0] = sc.x; scv[j*4+1] = sc.y; scv[j*4+2] = sc.z; scv[j*4+3] = sc.w;
    }

    // scaled first element of my segment, and of my right neighbor's segment
    const float xs_own0  = xv[0] * scv[0];
    const float xs_next0 = __shfl(xs_own0, (lane + 1) & 63); // lane 63: unused garbage
    const float xs0_g    = __shfl(xs_own0, 0);               // global xs[0] = carry_0

    // ---- Pass 1: per-segment affine map carry_out = A*carry_in + B ----
    // step i: carry_{i+1} = s_i*carry_i + c_i*xs_{i+1}
    float A = 1.0f, Bv = 0.0f;
    #pragma unroll
    for (int k = 0; k < 16; ++k) {
        float xn = (k < 15) ? xv[k+1] * scv[k+1] : xs_next0;
        Bv = fmaf(sv[k], Bv, cv[k] * xn);
        A  = sv[k] * A;
    }

    // ---- Inclusive scan over lanes (affine composition, Hillis-Steele) ----
    #pragma unroll
    for (int d = 1; d < 64; d <<= 1) {
        float Ar = __shfl_up(A,  d);
        float Br = __shfl_up(Bv, d);
        if (lane >= d) {
            Bv = fmaf(A, Br, Bv);   // new = cur ∘ recv
            A  = A * Ar;
        }
    }

    // carry at entry of my segment: apply lane (l-1) inclusive map to carry_0
    float Ap = __shfl_up(A,  1);
    float Bp = __shfl_up(Bv, 1);
    float carry = (lane == 0) ? xs0_g : fmaf(Ap, xs0_g, Bp);

    // ---- Pass 2: replay, emit outputs ----
    float outv[16];
    float out0_b = 0.0f;   // broadcast of out_0 (lane 0, k=0)
    float yfirst = 0.0f;   // new_first, valid on lane 63 after k=15
    #pragma unroll
    for (int k = 0; k < 16; ++k) {
        float xn = (k < 15) ? xv[k+1] * scv[k+1] : xs_next0;
        if (k == 15 && lane == 63) xn = out0_b;   // wrap: pairs with out_0
        float yk = fmaf(cv[k], carry, -sv[k] * xn);
        float nc = fmaf(sv[k], carry, cv[k] * xn);
        outv[k] = yk;
        carry = nc;
        if (k == 0)  out0_b = __shfl(yk, 0);      // straight-line, wave-uniform
        if (k == 15) yfirst = nc;                 // lane 63: s*carry_1023 + c*out_0
    }
    float yf = __shfl(yfirst, 63);
    if (lane == 0) outv[0] = yf;                  // y[0] = new_first

    // ---- residual subtract + store ----
    #pragma unroll
    for (int j = 0; j < 4; ++j) {
        float4 v;
        v.x = outv[j*4+0] - xv[j*4+0];
        v.y = outv[j*4+1] - xv[j*4+1];
        v.z = outv[j*4+2] - xv[j*4+2];
        v.w = outv[j*4+3] - xv[j*4+3];
        *reinterpret_cast<float4*>(out + rbase + j * 4) = v;
    }
}

extern "C" void kernel_launch(void* const* d_in, const int* in_sizes, int n_in,
                              void* d_out, int out_size, void* d_ws, size_t ws_size,
                              hipStream_t stream) {
    const float* x         = (const float*)d_in[0];
    const float* log_scale = (const float*)d_in[1];
    const float* theta     = (const float*)d_in[2];
    float* outp = (float*)d_out;

    float* tabc  = (float*)d_ws;
    float* tabs  = tabc + D;
    float* tabsc = tabs + D;

    const int nrows = in_sizes[0] / D;   // B*S = 32768

    rsa_make_tables<<<(D + 255) / 256, 256, 0, stream>>>(log_scale, theta, tabc, tabs, tabsc);

    const int grid = (nrows + 3) / 4;    // 4 waves per 256-thread block, 1 row/wave
    rsa_rot_kernel<<<grid, 256, 0, stream>>>(x, tabc, tabs, tabsc, outp, nrows);
}